// Round 1
// baseline (150.182 us; speedup 1.0000x reference)
//
#include <hip/hip_runtime.h>
#include <math.h>

#define NTHR 256
#define WAVES_PER_BLOCK 4

typedef __attribute__((ext_vector_type(8))) _Float16 f16x8;   // MFMA A/B frag (4 VGPRs)
typedef __attribute__((ext_vector_type(2))) _Float16 half2v;
typedef __attribute__((ext_vector_type(4))) float f32x4;      // MFMA C/D frag + packed math
typedef __attribute__((ext_vector_type(4))) unsigned uint4v;

#define CEXP 28.85390082f     // 20 * log2(e)
#define KLOG 0.03465735903f   // ln(2) / 20

// raw gfx950 transcendentals: only used for the one-time LDS table build
#define EXP2F(v) __builtin_amdgcn_exp2f(v)
#define LOG2F(v) __builtin_amdgcn_logf(v)

#if __has_builtin(__builtin_amdgcn_fractf)
#define FRACTF(v) __builtin_amdgcn_fractf(v)
#else
#define FRACTF(v) ((v) - floorf(v))
#endif

// ---- softplus/sigmoid LUT over az = CEXP*|z| ----
// entry j: az = j*TBL_STEP;  e = 2^-az
//   .x = KLOG * log2(1+e)   (softplus correction, so h = max(z,0) + .x)
//   .y = 1/(1+e)            (sigmoid magnitude, >= 0.5)
// Range az in [0, 20.46]: beyond that both saturate below 1e-6.
// Lerp error: s <= 2.3e-6, h <= ~1e-7  — far below the f16-tangent noise (2^-10).
#define TBL_N    1024
#define TBL_STEP 0.02f
#define KIDX     1442.695041f   /* CEXP / TBL_STEP */
#define TBL_MAX  1022.99f       /* clamp so j+1 <= 1023 */

static __device__ __forceinline__ f32x4 splat4(float v) { return (f32x4){v, v, v, v}; }

// LUT softplus(beta=20) + derivative, branch-free sign handling.
// ~12 full-rate VALU + 1 LDS read per element; zero transcendental-unit ops.
static __device__ __forceinline__ void act_lut4(const float2* __restrict__ t,
                                                f32x4 z, f32x4& h, f32x4& s) {
    #pragma unroll
    for (int i = 0; i < 4; ++i) {
        const float zi = z[i];
        float m = fminf(fabsf(zi) * KIDX, TBL_MAX);  // abs folds as src modifier
        const unsigned j = (unsigned)m;              // v_cvt_u32_f32 (trunc, m>=0)
        const float f = FRACTF(m);                   // v_fract_f32
        const float2 ea = t[j];
        const float2 eb = t[j + 1];                  // ds_read2_b64-mergeable
        const float l  = fmaf(f, eb.x - ea.x, ea.x);
        const float sm = fmaf(f, eb.y - ea.y, ea.y);
        h[i] = fmaxf(zi, 0.0f) + l;
        s[i] = 0.5f + copysignf(sm - 0.5f, zi);      // v_bfi_b32, no vcc
    }
}

// LUT sigmoid(20z) only (layer-3 derivative): reads just the .y lane
static __device__ __forceinline__ f32x4 sig_lut4(const float2* __restrict__ t, f32x4 z) {
    f32x4 s;
    #pragma unroll
    for (int i = 0; i < 4; ++i) {
        const float zi = z[i];
        float m = fminf(fabsf(zi) * KIDX, TBL_MAX);
        const unsigned j = (unsigned)m;
        const float f = FRACTF(m);
        const float sa = t[j].y;
        const float sb = t[j + 1].y;
        const float sm = fmaf(f, sb - sa, sa);
        s[i] = 0.5f + copysignf(sm - 0.5f, zi);
    }
    return s;
}

// pack 2 floats -> 2 f16 in one v_cvt_pkrtz_f16_f32
static __device__ __forceinline__ unsigned pk(float a, float b) {
    return __builtin_bit_cast(unsigned, __builtin_amdgcn_cvt_pkrtz(a, b));
}

// two f32x4 chunks -> single-f16 B operand (tangent streams)
static __device__ __forceinline__ f16x8 pack8v(const f32x4& a, const f32x4& b) {
    uint4v u = {pk(a[0], a[1]), pk(a[2], a[3]), pk(b[0], b[1]), pk(b[2], b[3])};
    return __builtin_bit_cast(f16x8, u);
}
// two f32x4 chunks -> f16 hi/lo split B operand (forward stream, residual ~2^-22)
static __device__ __forceinline__ void fsplit8v(const f32x4& a, const f32x4& b,
                                                f16x8& hi, f16x8& lo) {
    unsigned h[4], l[4];
    #pragma unroll
    for (int p2 = 0; p2 < 2; ++p2) {
        float u0 = a[2 * p2], u1 = a[2 * p2 + 1];
        unsigned hp = pk(u0, u1);
        half2v hh = __builtin_bit_cast(half2v, hp);
        h[p2] = hp;
        l[p2] = pk(u0 - (float)hh[0], u1 - (float)hh[1]);
        float w0 = b[2 * p2], w1 = b[2 * p2 + 1];
        unsigned hq = pk(w0, w1);
        half2v hh2 = __builtin_bit_cast(half2v, hq);
        h[2 + p2] = hq;
        l[2 + p2] = pk(w0 - (float)hh2[0], w1 - (float)hh2[1]);
    }
    hi = __builtin_bit_cast(f16x8, (uint4v){h[0], h[1], h[2], h[3]});
    lo = __builtin_bit_cast(f16x8, (uint4v){l[0], l[1], l[2], l[3]});
}

// forward, single-f16 weight: D += W*Bh + W*Bl
static __device__ __forceinline__ f32x4 mfma2f(f16x8 w, f16x8 bh, f16x8 bl, f32x4 c) {
    c = __builtin_amdgcn_mfma_f32_16x16x32_f16(w, bh, c, 0, 0, 0);
    c = __builtin_amdgcn_mfma_f32_16x16x32_f16(w, bl, c, 0, 0, 0);
    return c;
}
// tangent, single-f16 both sides: one MFMA
static __device__ __forceinline__ f32x4 mfma1t(f16x8 w, f16x8 b, f32x4 c) {
    return __builtin_amdgcn_mfma_f32_16x16x32_f16(w, b, c, 0, 0, 0);
}

__global__ void __launch_bounds__(NTHR)
presdiv_kernel(const float* __restrict__ x,
               const float* __restrict__ W1, const float* __restrict__ b1,
               const float* __restrict__ W2, const float* __restrict__ b2,
               const float* __restrict__ W3, const float* __restrict__ b3,
               const float* __restrict__ W4,
               float* __restrict__ out, int N)
{
    __shared__ float2 s_tbl[TBL_N];

    // ---- one-time LUT build (the only transcendentals in the kernel) ----
    for (int j = threadIdx.x; j < TBL_N; j += NTHR) {
        const float az = (float)j * TBL_STEP;
        const float e  = EXP2F(-az);
        const float p  = 1.0f + e;
        s_tbl[j] = make_float2(KLOG * LOG2F(p), 1.0f / p);
    }
    __syncthreads();

    const int lane = threadIdx.x & 63;
    const int wid  = threadIdx.x >> 6;
    const int n16  = lane & 15;        // sample-within-tile / MFMA col
    const int g    = lane >> 4;        // quad

    // ---- persistent weights (per lane), single f16 (RTN) ----
    f16x8 w2[2], w3[2];
    #pragma unroll
    for (int h = 0; h < 2; ++h) {
        #pragma unroll
        for (int j = 0; j < 8; ++j) {
            const int k2 = g * 8 + j;
            w2[h][j] = (_Float16)W2[k2 * 32 + 16 * h + n16];
            const int k3 = (j < 4) ? (4 * g + j) : (16 + 4 * g + (j - 4));
            w3[h][j] = (_Float16)W3[k3 * 32 + 16 * h + n16];
        }
    }
    // layer-1 rows + bias, vectorized in 2 chunks of 4 features
    f32x4 w1v[3][2], bb1v[2];
    #pragma unroll
    for (int c = 0; c < 2; ++c)
        #pragma unroll
        for (int i = 0; i < 4; ++i) {
            const int j = 4 * c + i;
            bb1v[c][i] = b1[g * 8 + j];
            #pragma unroll
            for (int d = 0; d < 3; ++d) w1v[d][c][i] = W1[d * 32 + g * 8 + j];
        }
    // C-layout biases + W4 column-vectors (k fixed, 4 rows per vector)
    f32x4 bb2v[2], bb3v[2], w4c[2][3];
    #pragma unroll
    for (int h = 0; h < 2; ++h)
        #pragma unroll
        for (int r = 0; r < 4; ++r) {
            const int row = 16 * h + 4 * g + r;
            bb2v[h][r] = b2[row];
            bb3v[h][r] = b3[row];
            #pragma unroll
            for (int k = 0; k < 3; ++k) w4c[h][k][r] = W4[row * 3 + k];
        }

    const int ntiles = (N + 15) >> 4;
    const int nwaves = gridDim.x * WAVES_PER_BLOCK;
    const f32x4 vzero = {0.f, 0.f, 0.f, 0.f};

    for (int tile = blockIdx.x * WAVES_PER_BLOCK + wid; tile < ntiles; tile += nwaves) {
        int s = tile * 16 + n16;
        if (s >= N) s = N - 1;
        const f32x4 X0 = splat4(x[3 * s + 0]);
        const f32x4 X1 = splat4(x[3 * s + 1]);
        const f32x4 X2 = splat4(x[3 * s + 2]);

        // ---- layer 1 (exact fp32, packed), directly in B-layout ----
        f32x4 vFv[2], v0v[2], v1v[2], v2v[2];
        #pragma unroll
        for (int c = 0; c < 2; ++c) {
            f32x4 z = __builtin_elementwise_fma(X0, w1v[0][c], bb1v[c]);
            z = __builtin_elementwise_fma(X1, w1v[1][c], z);
            z = __builtin_elementwise_fma(X2, w1v[2][c], z);
            f32x4 hv, sv;
            act_lut4(s_tbl, z, hv, sv);
            vFv[c] = hv;
            v0v[c] = sv * w1v[0][c];
            v1v[c] = sv * w1v[1][c];
            v2v[c] = sv * w1v[2][c];
        }

        // ---- layer 2 ----
        f32x4 aF[2], a0[2], a1[2], a2[2];
        aF[0] = bb2v[0]; aF[1] = bb2v[1];
        a0[0] = a0[1] = a1[0] = a1[1] = a2[0] = a2[1] = vzero;

        f16x8 bh, bl;
        fsplit8v(vFv[0], vFv[1], bh, bl);     // forward B: full split
        aF[0] = mfma2f(w2[0], bh, bl, aF[0]);
        aF[1] = mfma2f(w2[1], bh, bl, aF[1]);
        f16x8 tb = pack8v(v0v[0], v0v[1]);    // tangents: single f16
        a0[0] = mfma1t(w2[0], tb, a0[0]);
        a0[1] = mfma1t(w2[1], tb, a0[1]);
        tb = pack8v(v1v[0], v1v[1]);
        a1[0] = mfma1t(w2[0], tb, a1[0]);
        a1[1] = mfma1t(w2[1], tb, a1[1]);
        tb = pack8v(v2v[0], v2v[1]);
        a2[0] = mfma1t(w2[0], tb, a2[0]);
        a2[1] = mfma1t(w2[1], tb, a2[1]);

        // ---- boundary: act + diag-scale, packed, in C-layout ----
        #pragma unroll
        for (int h = 0; h < 2; ++h) {
            f32x4 hv, sv;
            act_lut4(s_tbl, aF[h], hv, sv);
            aF[h] = hv;                       // h2
            a0[h] *= sv;
            a1[h] *= sv;
            a2[h] *= sv;
        }

        // ---- layer 3: C-frags feed B directly (K-permuted weights) ----
        f32x4 zF[2], u0[2], u1[2], u2[2];
        zF[0] = bb3v[0]; zF[1] = bb3v[1];
        u0[0] = u0[1] = u1[0] = u1[1] = u2[0] = u2[1] = vzero;

        fsplit8v(aF[0], aF[1], bh, bl);
        zF[0] = mfma2f(w3[0], bh, bl, zF[0]);
        zF[1] = mfma2f(w3[1], bh, bl, zF[1]);
        tb = pack8v(a0[0], a0[1]);
        u0[0] = mfma1t(w3[0], tb, u0[0]);
        u0[1] = mfma1t(w3[1], tb, u0[1]);
        tb = pack8v(a1[0], a1[1]);
        u1[0] = mfma1t(w3[0], tb, u1[0]);
        u1[1] = mfma1t(w3[1], tb, u1[1]);
        tb = pack8v(a2[0], a2[1]);
        u2[0] = mfma1t(w3[0], tb, u2[0]);
        u2[1] = mfma1t(w3[1], tb, u2[1]);

        // ---- layer 4 + trace combine, packed across the 4 held rows ----
        // out0 = Σ t1*W4[:,0] + t2*W4[:,1]; out1 = Σ -t0*W4[:,0] + t2*W4[:,2];
        // out2 = Σ -t0*W4[:,1] - t1*W4[:,2]
        f32x4 O0 = vzero, O1 = vzero, O2 = vzero;
        #pragma unroll
        for (int h = 0; h < 2; ++h) {
            const f32x4 S  = sig_lut4(s_tbl, zF[h]);
            const f32x4 T0 = S * u0[h];
            const f32x4 T1 = S * u1[h];
            const f32x4 T2 = S * u2[h];
            O0 = __builtin_elementwise_fma(T1, w4c[h][0],
                 __builtin_elementwise_fma(T2, w4c[h][1], O0));
            O1 = __builtin_elementwise_fma(-T0, w4c[h][0],
                 __builtin_elementwise_fma(T2, w4c[h][2], O1));
            O2 = __builtin_elementwise_fma(-T0, w4c[h][1],
                 __builtin_elementwise_fma(-T1, w4c[h][2], O2));
        }
        float o0 = (O0[0] + O0[1]) + (O0[2] + O0[3]);
        float o1 = (O1[0] + O1[1]) + (O1[2] + O1[3]);
        float o2 = (O2[0] + O2[1]) + (O2[2] + O2[3]);

        o0 += __shfl_xor(o0, 16); o0 += __shfl_xor(o0, 32);
        o1 += __shfl_xor(o1, 16); o1 += __shfl_xor(o1, 32);
        o2 += __shfl_xor(o2, 16); o2 += __shfl_xor(o2, 32);

        if (g == 0) {
            out[3 * s + 0] = o0;
            out[3 * s + 1] = o1;
            out[3 * s + 2] = o2;
        }
    }
}

extern "C" void kernel_launch(void* const* d_in, const int* in_sizes, int n_in,
                              void* d_out, int out_size, void* d_ws, size_t ws_size,
                              hipStream_t stream)
{
    const float* x  = (const float*)d_in[0];
    const float* W1 = (const float*)d_in[1];
    const float* b1 = (const float*)d_in[2];
    const float* W2 = (const float*)d_in[3];
    const float* b2 = (const float*)d_in[4];
    const float* W3 = (const float*)d_in[5];
    const float* b3 = (const float*)d_in[6];
    const float* W4 = (const float*)d_in[7];
    // d_in[8] = b4 unused: constant offset cancels in the Jacobian.
    float* out = (float*)d_out;

    const int N = in_sizes[0] / 3;
    presdiv_kernel<<<4096, NTHR, 0, stream>>>(x, W1, b1, W2, b2, W3, b3, W4, out, N);
}

// Round 2
// 139.046 us; speedup vs baseline: 1.0801x; 1.0801x over previous
//
#include <hip/hip_runtime.h>
#include <math.h>

#define NTHR 256
#define WAVES_PER_BLOCK 4
#define NBLK 2048

typedef __attribute__((ext_vector_type(8))) _Float16 f16x8;   // MFMA A/B frag (4 VGPRs)
typedef __attribute__((ext_vector_type(2))) _Float16 half2v;
typedef __attribute__((ext_vector_type(4))) float f32x4;      // MFMA C/D frag + packed math
typedef __attribute__((ext_vector_type(4))) unsigned uint4v;

#define CEXP 28.85390082f     // 20 * log2(e)
#define KLOG 0.03465735903f   // ln(2) / 20

// raw gfx950 transcendentals: v_exp_f32 is 2^x, v_log_f32 is log2(x)
#define EXP2F(v) __builtin_amdgcn_exp2f(v)
#define LOG2F(v) __builtin_amdgcn_logf(v)

static __device__ __forceinline__ f32x4 splat4(float v) { return (f32x4){v, v, v, v}; }

// Vectorized softplus(beta=20) + derivative: non-transcendental arithmetic on
// f32x4 (compiler forms v_pk_*_f32), scalar loop only for exp2/log2.
// h = max(z,0) + KLOG*l, l = log2(1+2^(-|CEXP z|)); s = 1 - 2^(-CEXP*max(z,0) - l)
static __device__ __forceinline__ void act_hs4(f32x4 z, f32x4& h, f32x4& s) {
    f32x4 az = __builtin_elementwise_abs(splat4(CEXP) * z);
    f32x4 e;
    #pragma unroll
    for (int i = 0; i < 4; ++i) e[i] = EXP2F(-az[i]);
    f32x4 p = splat4(1.0f) + e;
    f32x4 l;
    #pragma unroll
    for (int i = 0; i < 4; ++i) l[i] = LOG2F(p[i]);
    f32x4 zp = __builtin_elementwise_max(z, splat4(0.0f));
    f32x4 q  = __builtin_elementwise_fma(splat4(-CEXP), zp, -l);
    f32x4 t;
    #pragma unroll
    for (int i = 0; i < 4; ++i) t[i] = EXP2F(q[i]);
    s = splat4(1.0f) - t;
    h = __builtin_elementwise_fma(splat4(KLOG), l, zp);
}

// sigmoid(20z) vectorized; select-free (exp2 overflow->inf, rcp(inf)->0)
static __device__ __forceinline__ f32x4 sigmoid4(f32x4 z) {
    f32x4 cz = splat4(-CEXP) * z;
    f32x4 e;
    #pragma unroll
    for (int i = 0; i < 4; ++i) e[i] = EXP2F(cz[i]);
    f32x4 p = splat4(1.0f) + e;
    f32x4 r;
    #pragma unroll
    for (int i = 0; i < 4; ++i) r[i] = __builtin_amdgcn_rcpf(p[i]);
    return r;
}

// pack 2 floats -> 2 f16 in one v_cvt_pkrtz_f16_f32
static __device__ __forceinline__ unsigned pk(float a, float b) {
    return __builtin_bit_cast(unsigned, __builtin_amdgcn_cvt_pkrtz(a, b));
}

// two f32x4 chunks -> single-f16 B operand (tangent streams)
static __device__ __forceinline__ f16x8 pack8v(const f32x4& a, const f32x4& b) {
    uint4v u = {pk(a[0], a[1]), pk(a[2], a[3]), pk(b[0], b[1]), pk(b[2], b[3])};
    return __builtin_bit_cast(f16x8, u);
}
// two f32x4 chunks -> f16 hi/lo split B operand (forward stream, residual ~2^-22)
static __device__ __forceinline__ void fsplit8v(const f32x4& a, const f32x4& b,
                                                f16x8& hi, f16x8& lo) {
    unsigned h[4], l[4];
    #pragma unroll
    for (int p2 = 0; p2 < 2; ++p2) {
        float u0 = a[2 * p2], u1 = a[2 * p2 + 1];
        unsigned hp = pk(u0, u1);
        half2v hh = __builtin_bit_cast(half2v, hp);
        h[p2] = hp;
        l[p2] = pk(u0 - (float)hh[0], u1 - (float)hh[1]);
        float w0 = b[2 * p2], w1 = b[2 * p2 + 1];
        unsigned hq = pk(w0, w1);
        half2v hh2 = __builtin_bit_cast(half2v, hq);
        h[2 + p2] = hq;
        l[2 + p2] = pk(w0 - (float)hh2[0], w1 - (float)hh2[1]);
    }
    hi = __builtin_bit_cast(f16x8, (uint4v){h[0], h[1], h[2], h[3]});
    lo = __builtin_bit_cast(f16x8, (uint4v){l[0], l[1], l[2], l[3]});
}

// forward, single-f16 weight: D += W*Bh + W*Bl
static __device__ __forceinline__ f32x4 mfma2f(f16x8 w, f16x8 bh, f16x8 bl, f32x4 c) {
    c = __builtin_amdgcn_mfma_f32_16x16x32_f16(w, bh, c, 0, 0, 0);
    c = __builtin_amdgcn_mfma_f32_16x16x32_f16(w, bl, c, 0, 0, 0);
    return c;
}
// tangent, single-f16 both sides: one MFMA
static __device__ __forceinline__ f32x4 mfma1t(f16x8 w, f16x8 b, f32x4 c) {
    return __builtin_amdgcn_mfma_f32_16x16x32_f16(w, b, c, 0, 0, 0);
}

__global__ void __launch_bounds__(NTHR)
presdiv_kernel(const float* __restrict__ x,
               const float* __restrict__ W1, const float* __restrict__ b1,
               const float* __restrict__ W2, const float* __restrict__ b2,
               const float* __restrict__ W3, const float* __restrict__ b3,
               const float* __restrict__ W4,
               float* __restrict__ out, int N)
{
    const int lane = threadIdx.x & 63;
    const int wid  = threadIdx.x >> 6;
    const int n16  = lane & 15;        // sample-within-tile / MFMA col
    const int g    = lane >> 4;        // quad

    // ---- persistent weights (per lane), single f16 (RTN) ----
    f16x8 w2[2], w3[2];
    #pragma unroll
    for (int h = 0; h < 2; ++h) {
        #pragma unroll
        for (int j = 0; j < 8; ++j) {
            const int k2 = g * 8 + j;
            w2[h][j] = (_Float16)W2[k2 * 32 + 16 * h + n16];
            const int k3 = (j < 4) ? (4 * g + j) : (16 + 4 * g + (j - 4));
            w3[h][j] = (_Float16)W3[k3 * 32 + 16 * h + n16];
        }
    }
    // layer-1 rows + bias, vectorized in 2 chunks of 4 features
    f32x4 w1v[3][2], bb1v[2];
    #pragma unroll
    for (int c = 0; c < 2; ++c)
        #pragma unroll
        for (int i = 0; i < 4; ++i) {
            const int j = 4 * c + i;
            bb1v[c][i] = b1[g * 8 + j];
            #pragma unroll
            for (int d = 0; d < 3; ++d) w1v[d][c][i] = W1[d * 32 + g * 8 + j];
        }
    // C-layout biases + W4 column-vectors (k fixed, 4 rows per vector)
    f32x4 bb2v[2], bb3v[2], w4c[2][3];
    #pragma unroll
    for (int h = 0; h < 2; ++h)
        #pragma unroll
        for (int r = 0; r < 4; ++r) {
            const int row = 16 * h + 4 * g + r;
            bb2v[h][r] = b2[row];
            bb3v[h][r] = b3[row];
            #pragma unroll
            for (int k = 0; k < 3; ++k) w4c[h][k][r] = W4[row * 3 + k];
        }

    const int ntiles = (N + 15) >> 4;
    const int npairs = (ntiles + 1) >> 1;
    const int nwaves = gridDim.x * WAVES_PER_BLOCK;
    const f32x4 vzero = {0.f, 0.f, 0.f, 0.f};

    // Two independent tiles per iteration (unroll-and-jam): doubles per-wave
    // ILP so the serial act->MFMA->act->MFMA chain of one tile hides under
    // the other. All [u]-indexed loops are fully unrolled (static indices).
    for (int tp = blockIdx.x * WAVES_PER_BLOCK + wid; tp < npairs; tp += nwaves) {
        int sU[2];
        #pragma unroll
        for (int u = 0; u < 2; ++u) {
            int t = 2 * tp + u;
            if (t >= ntiles) t = ntiles - 1;   // duplicate-compute tail (benign)
            int s = t * 16 + n16;
            if (s >= N) s = N - 1;
            sU[u] = s;
        }

        // ---- layer 1 (exact fp32, packed), directly in B-layout ----
        f32x4 vFv[2][2], v0v[2][2], v1v[2][2], v2v[2][2];
        #pragma unroll
        for (int u = 0; u < 2; ++u) {
            const f32x4 X0 = splat4(x[3 * sU[u] + 0]);
            const f32x4 X1 = splat4(x[3 * sU[u] + 1]);
            const f32x4 X2 = splat4(x[3 * sU[u] + 2]);
            #pragma unroll
            for (int c = 0; c < 2; ++c) {
                f32x4 z = __builtin_elementwise_fma(X0, w1v[0][c], bb1v[c]);
                z = __builtin_elementwise_fma(X1, w1v[1][c], z);
                z = __builtin_elementwise_fma(X2, w1v[2][c], z);
                f32x4 hv, sv;
                act_hs4(z, hv, sv);
                vFv[u][c] = hv;
                v0v[u][c] = sv * w1v[0][c];
                v1v[u][c] = sv * w1v[1][c];
                v2v[u][c] = sv * w1v[2][c];
            }
        }

        // ---- layer 2 ----
        f32x4 aF[2][2], a0[2][2], a1[2][2], a2[2][2];
        #pragma unroll
        for (int u = 0; u < 2; ++u) {
            aF[u][0] = bb2v[0]; aF[u][1] = bb2v[1];
            a0[u][0] = a0[u][1] = a1[u][0] = a1[u][1] = a2[u][0] = a2[u][1] = vzero;

            f16x8 bh, bl, tb;
            fsplit8v(vFv[u][0], vFv[u][1], bh, bl);   // forward B: full split
            aF[u][0] = mfma2f(w2[0], bh, bl, aF[u][0]);
            aF[u][1] = mfma2f(w2[1], bh, bl, aF[u][1]);
            tb = pack8v(v0v[u][0], v0v[u][1]);        // tangents: single f16
            a0[u][0] = mfma1t(w2[0], tb, a0[u][0]);
            a0[u][1] = mfma1t(w2[1], tb, a0[u][1]);
            tb = pack8v(v1v[u][0], v1v[u][1]);
            a1[u][0] = mfma1t(w2[0], tb, a1[u][0]);
            a1[u][1] = mfma1t(w2[1], tb, a1[u][1]);
            tb = pack8v(v2v[u][0], v2v[u][1]);
            a2[u][0] = mfma1t(w2[0], tb, a2[u][0]);
            a2[u][1] = mfma1t(w2[1], tb, a2[u][1]);
        }

        // ---- boundary: act + diag-scale, packed, in C-layout ----
        #pragma unroll
        for (int u = 0; u < 2; ++u)
            #pragma unroll
            for (int h = 0; h < 2; ++h) {
                f32x4 hv, sv;
                act_hs4(aF[u][h], hv, sv);
                aF[u][h] = hv;                        // h2
                a0[u][h] *= sv;
                a1[u][h] *= sv;
                a2[u][h] *= sv;
            }

        // ---- layer 3: C-frags feed B directly (K-permuted weights) ----
        f32x4 zF[2][2], u0[2][2], u1[2][2], u2[2][2];
        #pragma unroll
        for (int u = 0; u < 2; ++u) {
            zF[u][0] = bb3v[0]; zF[u][1] = bb3v[1];
            u0[u][0] = u0[u][1] = u1[u][0] = u1[u][1] = u2[u][0] = u2[u][1] = vzero;

            f16x8 bh, bl, tb;
            fsplit8v(aF[u][0], aF[u][1], bh, bl);
            zF[u][0] = mfma2f(w3[0], bh, bl, zF[u][0]);
            zF[u][1] = mfma2f(w3[1], bh, bl, zF[u][1]);
            tb = pack8v(a0[u][0], a0[u][1]);
            u0[u][0] = mfma1t(w3[0], tb, u0[u][0]);
            u0[u][1] = mfma1t(w3[1], tb, u0[u][1]);
            tb = pack8v(a1[u][0], a1[u][1]);
            u1[u][0] = mfma1t(w3[0], tb, u1[u][0]);
            u1[u][1] = mfma1t(w3[1], tb, u1[u][1]);
            tb = pack8v(a2[u][0], a2[u][1]);
            u2[u][0] = mfma1t(w3[0], tb, u2[u][0]);
            u2[u][1] = mfma1t(w3[1], tb, u2[u][1]);
        }

        // ---- layer 4 + trace combine, packed across the 4 held rows ----
        // out0 = Σ t1*W4[:,0] + t2*W4[:,1]; out1 = Σ -t0*W4[:,0] + t2*W4[:,2];
        // out2 = Σ -t0*W4[:,1] - t1*W4[:,2]
        #pragma unroll
        for (int u = 0; u < 2; ++u) {
            f32x4 O0 = vzero, O1 = vzero, O2 = vzero;
            #pragma unroll
            for (int h = 0; h < 2; ++h) {
                const f32x4 S  = sigmoid4(zF[u][h]);
                const f32x4 T0 = S * u0[u][h];
                const f32x4 T1 = S * u1[u][h];
                const f32x4 T2 = S * u2[u][h];
                O0 = __builtin_elementwise_fma(T1, w4c[h][0],
                     __builtin_elementwise_fma(T2, w4c[h][1], O0));
                O1 = __builtin_elementwise_fma(-T0, w4c[h][0],
                     __builtin_elementwise_fma(T2, w4c[h][2], O1));
                O2 = __builtin_elementwise_fma(-T0, w4c[h][1],
                     __builtin_elementwise_fma(-T1, w4c[h][2], O2));
            }
            float o0 = (O0[0] + O0[1]) + (O0[2] + O0[3]);
            float o1 = (O1[0] + O1[1]) + (O1[2] + O1[3]);
            float o2 = (O2[0] + O2[1]) + (O2[2] + O2[3]);

            o0 += __shfl_xor(o0, 16); o0 += __shfl_xor(o0, 32);
            o1 += __shfl_xor(o1, 16); o1 += __shfl_xor(o1, 32);
            o2 += __shfl_xor(o2, 16); o2 += __shfl_xor(o2, 32);

            if (g == 0) {
                out[3 * sU[u] + 0] = o0;
                out[3 * sU[u] + 1] = o1;
                out[3 * sU[u] + 2] = o2;
            }
        }
    }
}

extern "C" void kernel_launch(void* const* d_in, const int* in_sizes, int n_in,
                              void* d_out, int out_size, void* d_ws, size_t ws_size,
                              hipStream_t stream)
{
    const float* x  = (const float*)d_in[0];
    const float* W1 = (const float*)d_in[1];
    const float* b1 = (const float*)d_in[2];
    const float* W2 = (const float*)d_in[3];
    const float* b2 = (const float*)d_in[4];
    const float* W3 = (const float*)d_in[5];
    const float* b3 = (const float*)d_in[6];
    const float* W4 = (const float*)d_in[7];
    // d_in[8] = b4 unused: constant offset cancels in the Jacobian.
    float* out = (float*)d_out;

    const int N = in_sizes[0] / 3;
    presdiv_kernel<<<NBLK, NTHR, 0, stream>>>(x, W1, b1, W2, b2, W3, b3, W4, out, N);
}

// Round 3
// 137.784 us; speedup vs baseline: 1.0900x; 1.0092x over previous
//
#include <hip/hip_runtime.h>
#include <math.h>

#define NTHR 256
#define WAVES_PER_BLOCK 4
#define NBLK 4096

typedef __attribute__((ext_vector_type(8))) _Float16 f16x8;   // MFMA A/B frag (4 VGPRs)
typedef __attribute__((ext_vector_type(2))) _Float16 half2v;
typedef __attribute__((ext_vector_type(4))) float f32x4;      // MFMA C/D frag + packed math
typedef __attribute__((ext_vector_type(4))) unsigned uint4v;

#define CEXP 28.85390082f     // 20 * log2(e)

// raw gfx950 transcendental: v_exp_f32 is 2^x (the ONLY trans op left per element)
#define EXP2F(v) __builtin_amdgcn_exp2f(v)

// Degree-5 Chebyshev fits on e = 2^(-CEXP|z|) in [0,1] (register-only, no LDS):
//   L(e) ~= ln(1+e),        |err| <= 1.1e-5  -> h = max(z,0) + L/20
//   R(e) ~= 1/(1+e) - 0.5,  |err| <= 5e-5    -> s = 0.5 + copysign(R, z)
// Validated at e in {0, .25, .5, .75, 1}. Errors are ~100x below the f16
// tangent quantization (2^-11) that dominates the output absmax.
#define LP0 0.0000101f
#define LP1 0.9992412f
#define LP2 -0.4902368f
#define LP3 0.2852352f
#define LP4 -0.1315072f
#define LP5 0.0304128f

#define SP0 0.4999565f
#define SP1 -0.9966232f
#define SP2 0.9560768f
#define SP3 -0.7777832f
#define SP4 0.4259936f
#define SP5 -0.1076512f

static __device__ __forceinline__ f32x4 splat4(float v) { return (f32x4){v, v, v, v}; }

static __device__ __forceinline__ f32x4 poly5(f32x4 e, float c5, float c4, float c3,
                                              float c2, float c1, float c0) {
    f32x4 r = __builtin_elementwise_fma(splat4(c5), e, splat4(c4));
    r = __builtin_elementwise_fma(r, e, splat4(c3));
    r = __builtin_elementwise_fma(r, e, splat4(c2));
    r = __builtin_elementwise_fma(r, e, splat4(c1));
    r = __builtin_elementwise_fma(r, e, splat4(c0));
    return r;
}

static __device__ __forceinline__ f32x4 copysign4(f32x4 mag, f32x4 sgn) {
    f32x4 r;
    #pragma unroll
    for (int i = 0; i < 4; ++i) r[i] = __builtin_copysignf(mag[i], sgn[i]);  // v_bfi_b32
    return r;
}

// softplus(beta=20) value + derivative: 4 exp2 per chunk (was 12 trans),
// everything else full-rate FMA that packs as v_pk_*_f32.
static __device__ __forceinline__ void act_hs4(f32x4 z, f32x4& h, f32x4& s) {
    f32x4 naz = -__builtin_elementwise_abs(splat4(CEXP) * z);
    f32x4 e;
    #pragma unroll
    for (int i = 0; i < 4; ++i) e[i] = EXP2F(naz[i]);
    const f32x4 L = poly5(e, LP5, LP4, LP3, LP2, LP1, LP0);
    const f32x4 R = poly5(e, SP5, SP4, SP3, SP2, SP1, SP0);
    const f32x4 zp = __builtin_elementwise_max(z, splat4(0.0f));
    h = __builtin_elementwise_fma(L, splat4(0.05f), zp);
    s = splat4(0.5f) + copysign4(R, z);
}

// sigmoid(20z): 4 exp2 per chunk (was 4 exp2 + 4 rcp)
static __device__ __forceinline__ f32x4 sigmoid4(f32x4 z) {
    f32x4 naz = -__builtin_elementwise_abs(splat4(CEXP) * z);
    f32x4 e;
    #pragma unroll
    for (int i = 0; i < 4; ++i) e[i] = EXP2F(naz[i]);
    const f32x4 R = poly5(e, SP5, SP4, SP3, SP2, SP1, SP0);
    return splat4(0.5f) + copysign4(R, z);
}

// pack 2 floats -> 2 f16 in one v_cvt_pkrtz_f16_f32
static __device__ __forceinline__ unsigned pk(float a, float b) {
    return __builtin_bit_cast(unsigned, __builtin_amdgcn_cvt_pkrtz(a, b));
}

// two f32x4 chunks -> single-f16 B operand (tangent streams)
static __device__ __forceinline__ f16x8 pack8v(const f32x4& a, const f32x4& b) {
    uint4v u = {pk(a[0], a[1]), pk(a[2], a[3]), pk(b[0], b[1]), pk(b[2], b[3])};
    return __builtin_bit_cast(f16x8, u);
}
// two f32x4 chunks -> f16 hi/lo split B operand (forward stream, residual ~2^-22)
static __device__ __forceinline__ void fsplit8v(const f32x4& a, const f32x4& b,
                                                f16x8& hi, f16x8& lo) {
    unsigned h[4], l[4];
    #pragma unroll
    for (int p2 = 0; p2 < 2; ++p2) {
        float u0 = a[2 * p2], u1 = a[2 * p2 + 1];
        unsigned hp = pk(u0, u1);
        half2v hh = __builtin_bit_cast(half2v, hp);
        h[p2] = hp;
        l[p2] = pk(u0 - (float)hh[0], u1 - (float)hh[1]);
        float w0 = b[2 * p2], w1 = b[2 * p2 + 1];
        unsigned hq = pk(w0, w1);
        half2v hh2 = __builtin_bit_cast(half2v, hq);
        h[2 + p2] = hq;
        l[2 + p2] = pk(w0 - (float)hh2[0], w1 - (float)hh2[1]);
    }
    hi = __builtin_bit_cast(f16x8, (uint4v){h[0], h[1], h[2], h[3]});
    lo = __builtin_bit_cast(f16x8, (uint4v){l[0], l[1], l[2], l[3]});
}

// forward, single-f16 weight: D += W*Bh + W*Bl
static __device__ __forceinline__ f32x4 mfma2f(f16x8 w, f16x8 bh, f16x8 bl, f32x4 c) {
    c = __builtin_amdgcn_mfma_f32_16x16x32_f16(w, bh, c, 0, 0, 0);
    c = __builtin_amdgcn_mfma_f32_16x16x32_f16(w, bl, c, 0, 0, 0);
    return c;
}
// tangent, single-f16 both sides: one MFMA
static __device__ __forceinline__ f32x4 mfma1t(f16x8 w, f16x8 b, f32x4 c) {
    return __builtin_amdgcn_mfma_f32_16x16x32_f16(w, b, c, 0, 0, 0);
}

__global__ void __launch_bounds__(NTHR)
presdiv_kernel(const float* __restrict__ x,
               const float* __restrict__ W1, const float* __restrict__ b1,
               const float* __restrict__ W2, const float* __restrict__ b2,
               const float* __restrict__ W3, const float* __restrict__ b3,
               const float* __restrict__ W4,
               float* __restrict__ out, int N)
{
    const int lane = threadIdx.x & 63;
    const int wid  = threadIdx.x >> 6;
    const int n16  = lane & 15;        // sample-within-tile / MFMA col
    const int g    = lane >> 4;        // quad

    // ---- persistent weights (per lane), single f16 (RTN) ----
    f16x8 w2[2], w3[2];
    #pragma unroll
    for (int h = 0; h < 2; ++h) {
        #pragma unroll
        for (int j = 0; j < 8; ++j) {
            const int k2 = g * 8 + j;
            w2[h][j] = (_Float16)W2[k2 * 32 + 16 * h + n16];
            const int k3 = (j < 4) ? (4 * g + j) : (16 + 4 * g + (j - 4));
            w3[h][j] = (_Float16)W3[k3 * 32 + 16 * h + n16];
        }
    }
    // layer-1 rows + bias, vectorized in 2 chunks of 4 features
    f32x4 w1v[3][2], bb1v[2];
    #pragma unroll
    for (int c = 0; c < 2; ++c)
        #pragma unroll
        for (int i = 0; i < 4; ++i) {
            const int j = 4 * c + i;
            bb1v[c][i] = b1[g * 8 + j];
            #pragma unroll
            for (int d = 0; d < 3; ++d) w1v[d][c][i] = W1[d * 32 + g * 8 + j];
        }
    // C-layout biases + W4 column-vectors (k fixed, 4 rows per vector)
    f32x4 bb2v[2], bb3v[2], w4c[2][3];
    #pragma unroll
    for (int h = 0; h < 2; ++h)
        #pragma unroll
        for (int r = 0; r < 4; ++r) {
            const int row = 16 * h + 4 * g + r;
            bb2v[h][r] = b2[row];
            bb3v[h][r] = b3[row];
            #pragma unroll
            for (int k = 0; k < 3; ++k) w4c[h][k][r] = W4[row * 3 + k];
        }

    const int ntiles = (N + 15) >> 4;
    const int nwaves = gridDim.x * WAVES_PER_BLOCK;
    const f32x4 vzero = {0.f, 0.f, 0.f, 0.f};

    const int tstart = blockIdx.x * WAVES_PER_BLOCK + wid;
    if (tstart >= ntiles) return;

    // software-pipelined x: preload current iteration's 3 floats
    int s0 = tstart * 16 + n16; if (s0 >= N) s0 = N - 1;
    float Xc0 = x[3 * s0 + 0], Xc1 = x[3 * s0 + 1], Xc2 = x[3 * s0 + 2];

    for (int tile = tstart; tile < ntiles; tile += nwaves) {
        int s = tile * 16 + n16;
        if (s >= N) s = N - 1;

        // ---- prefetch next iteration's x (clamped, branch-free) ----
        int tn = tile + nwaves; if (tn >= ntiles) tn = ntiles - 1;
        int sn = tn * 16 + n16; if (sn >= N) sn = N - 1;
        const float Xn0 = x[3 * sn + 0];
        const float Xn1 = x[3 * sn + 1];
        const float Xn2 = x[3 * sn + 2];

        const f32x4 X0 = splat4(Xc0);
        const f32x4 X1 = splat4(Xc1);
        const f32x4 X2 = splat4(Xc2);

        // ---- layer 1 (exact fp32, packed), directly in B-layout ----
        f32x4 vFv[2], v0v[2], v1v[2], v2v[2];
        #pragma unroll
        for (int c = 0; c < 2; ++c) {
            f32x4 z = __builtin_elementwise_fma(X0, w1v[0][c], bb1v[c]);
            z = __builtin_elementwise_fma(X1, w1v[1][c], z);
            z = __builtin_elementwise_fma(X2, w1v[2][c], z);
            f32x4 hv, sv;
            act_hs4(z, hv, sv);
            vFv[c] = hv;
            v0v[c] = sv * w1v[0][c];
            v1v[c] = sv * w1v[1][c];
            v2v[c] = sv * w1v[2][c];
        }

        // ---- layer 2 ----
        f32x4 aF[2], a0[2], a1[2], a2[2];
        aF[0] = bb2v[0]; aF[1] = bb2v[1];
        a0[0] = a0[1] = a1[0] = a1[1] = a2[0] = a2[1] = vzero;

        f16x8 bh, bl;
        fsplit8v(vFv[0], vFv[1], bh, bl);     // forward B: full split
        aF[0] = mfma2f(w2[0], bh, bl, aF[0]);
        aF[1] = mfma2f(w2[1], bh, bl, aF[1]);
        f16x8 tb = pack8v(v0v[0], v0v[1]);    // tangents: single f16
        a0[0] = mfma1t(w2[0], tb, a0[0]);
        a0[1] = mfma1t(w2[1], tb, a0[1]);
        tb = pack8v(v1v[0], v1v[1]);
        a1[0] = mfma1t(w2[0], tb, a1[0]);
        a1[1] = mfma1t(w2[1], tb, a1[1]);
        tb = pack8v(v2v[0], v2v[1]);
        a2[0] = mfma1t(w2[0], tb, a2[0]);
        a2[1] = mfma1t(w2[1], tb, a2[1]);

        // ---- boundary: act + diag-scale, packed, in C-layout ----
        #pragma unroll
        for (int h = 0; h < 2; ++h) {
            f32x4 hv, sv;
            act_hs4(aF[h], hv, sv);
            aF[h] = hv;                       // h2
            a0[h] *= sv;
            a1[h] *= sv;
            a2[h] *= sv;
        }

        // ---- layer 3: C-frags feed B directly (K-permuted weights) ----
        f32x4 zF[2], u0[2], u1[2], u2[2];
        zF[0] = bb3v[0]; zF[1] = bb3v[1];
        u0[0] = u0[1] = u1[0] = u1[1] = u2[0] = u2[1] = vzero;

        fsplit8v(aF[0], aF[1], bh, bl);
        zF[0] = mfma2f(w3[0], bh, bl, zF[0]);
        zF[1] = mfma2f(w3[1], bh, bl, zF[1]);
        tb = pack8v(a0[0], a0[1]);
        u0[0] = mfma1t(w3[0], tb, u0[0]);
        u0[1] = mfma1t(w3[1], tb, u0[1]);
        tb = pack8v(a1[0], a1[1]);
        u1[0] = mfma1t(w3[0], tb, u1[0]);
        u1[1] = mfma1t(w3[1], tb, u1[1]);
        tb = pack8v(a2[0], a2[1]);
        u2[0] = mfma1t(w3[0], tb, u2[0]);
        u2[1] = mfma1t(w3[1], tb, u2[1]);

        // ---- layer 4 + trace combine, packed across the 4 held rows ----
        // out0 = Σ t1*W4[:,0] + t2*W4[:,1]; out1 = Σ -t0*W4[:,0] + t2*W4[:,2];
        // out2 = Σ -t0*W4[:,1] - t1*W4[:,2]
        f32x4 O0 = vzero, O1 = vzero, O2 = vzero;
        #pragma unroll
        for (int h = 0; h < 2; ++h) {
            const f32x4 S  = sigmoid4(zF[h]);
            const f32x4 T0 = S * u0[h];
            const f32x4 T1 = S * u1[h];
            const f32x4 T2 = S * u2[h];
            O0 = __builtin_elementwise_fma(T1, w4c[h][0],
                 __builtin_elementwise_fma(T2, w4c[h][1], O0));
            O1 = __builtin_elementwise_fma(-T0, w4c[h][0],
                 __builtin_elementwise_fma(T2, w4c[h][2], O1));
            O2 = __builtin_elementwise_fma(-T0, w4c[h][1],
                 __builtin_elementwise_fma(-T1, w4c[h][2], O2));
        }
        float o0 = (O0[0] + O0[1]) + (O0[2] + O0[3]);
        float o1 = (O1[0] + O1[1]) + (O1[2] + O1[3]);
        float o2 = (O2[0] + O2[1]) + (O2[2] + O2[3]);

        o0 += __shfl_xor(o0, 16); o0 += __shfl_xor(o0, 32);
        o1 += __shfl_xor(o1, 16); o1 += __shfl_xor(o1, 32);
        o2 += __shfl_xor(o2, 16); o2 += __shfl_xor(o2, 32);

        if (g == 0) {
            out[3 * s + 0] = o0;
            out[3 * s + 1] = o1;
            out[3 * s + 2] = o2;
        }

        Xc0 = Xn0; Xc1 = Xn1; Xc2 = Xn2;
    }
}

extern "C" void kernel_launch(void* const* d_in, const int* in_sizes, int n_in,
                              void* d_out, int out_size, void* d_ws, size_t ws_size,
                              hipStream_t stream)
{
    const float* x  = (const float*)d_in[0];
    const float* W1 = (const float*)d_in[1];
    const float* b1 = (const float*)d_in[2];
    const float* W2 = (const float*)d_in[3];
    const float* b2 = (const float*)d_in[4];
    const float* W3 = (const float*)d_in[5];
    const float* b3 = (const float*)d_in[6];
    const float* W4 = (const float*)d_in[7];
    // d_in[8] = b4 unused: constant offset cancels in the Jacobian.
    float* out = (float*)d_out;

    const int N = in_sizes[0] / 3;
    presdiv_kernel<<<NBLK, NTHR, 0, stream>>>(x, W1, b1, W2, b2, W3, b3, W4, out, N);
}

// Round 4
// 137.165 us; speedup vs baseline: 1.0949x; 1.0045x over previous
//
#include <hip/hip_runtime.h>
#include <math.h>

#define NTHR 512              // 8 waves/block: more resident waves per CU if the
#define WAVES_PER_BLOCK 8     // ~2-workgroups/CU residency cap is real
#define NBLK 2048             // same total waves (16384) / tiles-per-wave as R0

typedef __attribute__((ext_vector_type(8))) _Float16 f16x8;   // MFMA A/B frag (4 VGPRs)
typedef __attribute__((ext_vector_type(2))) _Float16 half2v;
typedef __attribute__((ext_vector_type(4))) float f32x4;      // MFMA C/D frag + packed math
typedef __attribute__((ext_vector_type(4))) unsigned uint4v;

#define CEXP 28.85390082f     // 20 * log2(e)
#define KLOG 0.03465735903f   // ln(2) / 20

// raw gfx950 transcendentals: v_exp_f32 is 2^x, v_log_f32 is log2(x)
// (measured across R0/R3: near full-rate issue — keep them, they beat polys)
#define EXP2F(v) __builtin_amdgcn_exp2f(v)
#define LOG2F(v) __builtin_amdgcn_logf(v)

static __device__ __forceinline__ f32x4 splat4(float v) { return (f32x4){v, v, v, v}; }

// Vectorized softplus(beta=20) + derivative: non-transcendental arithmetic on
// f32x4 (compiler forms v_pk_*_f32), scalar loop only for exp2/log2.
// h = max(z,0) + KLOG*l, l = log2(1+2^(-|CEXP z|)); s = 1 - 2^(-CEXP*max(z,0) - l)
static __device__ __forceinline__ void act_hs4(f32x4 z, f32x4& h, f32x4& s) {
    f32x4 az = __builtin_elementwise_abs(splat4(CEXP) * z);
    f32x4 e;
    #pragma unroll
    for (int i = 0; i < 4; ++i) e[i] = EXP2F(-az[i]);
    f32x4 p = splat4(1.0f) + e;
    f32x4 l;
    #pragma unroll
    for (int i = 0; i < 4; ++i) l[i] = LOG2F(p[i]);
    f32x4 zp = __builtin_elementwise_max(z, splat4(0.0f));
    f32x4 q  = __builtin_elementwise_fma(splat4(-CEXP), zp, -l);
    f32x4 t;
    #pragma unroll
    for (int i = 0; i < 4; ++i) t[i] = EXP2F(q[i]);
    s = splat4(1.0f) - t;
    h = __builtin_elementwise_fma(splat4(KLOG), l, zp);
}

// sigmoid(20z) vectorized; select-free (exp2 overflow->inf, rcp(inf)->0)
static __device__ __forceinline__ f32x4 sigmoid4(f32x4 z) {
    f32x4 cz = splat4(-CEXP) * z;
    f32x4 e;
    #pragma unroll
    for (int i = 0; i < 4; ++i) e[i] = EXP2F(cz[i]);
    f32x4 p = splat4(1.0f) + e;
    f32x4 r;
    #pragma unroll
    for (int i = 0; i < 4; ++i) r[i] = __builtin_amdgcn_rcpf(p[i]);
    return r;
}

// pack 2 floats -> 2 f16 in one v_cvt_pkrtz_f16_f32
static __device__ __forceinline__ unsigned pk(float a, float b) {
    return __builtin_bit_cast(unsigned, __builtin_amdgcn_cvt_pkrtz(a, b));
}

// two f32x4 chunks -> single-f16 B operand (tangent streams)
static __device__ __forceinline__ f16x8 pack8v(const f32x4& a, const f32x4& b) {
    uint4v u = {pk(a[0], a[1]), pk(a[2], a[3]), pk(b[0], b[1]), pk(b[2], b[3])};
    return __builtin_bit_cast(f16x8, u);
}
// two f32x4 chunks -> f16 hi/lo split B operand (forward stream, residual ~2^-22)
static __device__ __forceinline__ void fsplit8v(const f32x4& a, const f32x4& b,
                                                f16x8& hi, f16x8& lo) {
    unsigned h[4], l[4];
    #pragma unroll
    for (int p2 = 0; p2 < 2; ++p2) {
        float u0 = a[2 * p2], u1 = a[2 * p2 + 1];
        unsigned hp = pk(u0, u1);
        half2v hh = __builtin_bit_cast(half2v, hp);
        h[p2] = hp;
        l[p2] = pk(u0 - (float)hh[0], u1 - (float)hh[1]);
        float w0 = b[2 * p2], w1 = b[2 * p2 + 1];
        unsigned hq = pk(w0, w1);
        half2v hh2 = __builtin_bit_cast(half2v, hq);
        h[2 + p2] = hq;
        l[2 + p2] = pk(w0 - (float)hh2[0], w1 - (float)hh2[1]);
    }
    hi = __builtin_bit_cast(f16x8, (uint4v){h[0], h[1], h[2], h[3]});
    lo = __builtin_bit_cast(f16x8, (uint4v){l[0], l[1], l[2], l[3]});
}

// forward, single-f16 weight: D += W*Bh + W*Bl
static __device__ __forceinline__ f32x4 mfma2f(f16x8 w, f16x8 bh, f16x8 bl, f32x4 c) {
    c = __builtin_amdgcn_mfma_f32_16x16x32_f16(w, bh, c, 0, 0, 0);
    c = __builtin_amdgcn_mfma_f32_16x16x32_f16(w, bl, c, 0, 0, 0);
    return c;
}
// tangent, single-f16 both sides: one MFMA
static __device__ __forceinline__ f32x4 mfma1t(f16x8 w, f16x8 b, f32x4 c) {
    return __builtin_amdgcn_mfma_f32_16x16x32_f16(w, b, c, 0, 0, 0);
}

__global__ void __launch_bounds__(NTHR)
presdiv_kernel(const float* __restrict__ x,
               const float* __restrict__ W1, const float* __restrict__ b1,
               const float* __restrict__ W2, const float* __restrict__ b2,
               const float* __restrict__ W3, const float* __restrict__ b3,
               const float* __restrict__ W4,
               float* __restrict__ out, int N)
{
    const int lane = threadIdx.x & 63;
    const int wid  = threadIdx.x >> 6;
    const int n16  = lane & 15;        // sample-within-tile / MFMA col
    const int g    = lane >> 4;        // quad

    // ---- persistent weights (per lane), single f16 (RTN) ----
    f16x8 w2[2], w3[2];
    #pragma unroll
    for (int h = 0; h < 2; ++h) {
        #pragma unroll
        for (int j = 0; j < 8; ++j) {
            const int k2 = g * 8 + j;
            w2[h][j] = (_Float16)W2[k2 * 32 + 16 * h + n16];
            const int k3 = (j < 4) ? (4 * g + j) : (16 + 4 * g + (j - 4));
            w3[h][j] = (_Float16)W3[k3 * 32 + 16 * h + n16];
        }
    }
    // layer-1 rows + bias, vectorized in 2 chunks of 4 features
    f32x4 w1v[3][2], bb1v[2];
    #pragma unroll
    for (int c = 0; c < 2; ++c)
        #pragma unroll
        for (int i = 0; i < 4; ++i) {
            const int j = 4 * c + i;
            bb1v[c][i] = b1[g * 8 + j];
            #pragma unroll
            for (int d = 0; d < 3; ++d) w1v[d][c][i] = W1[d * 32 + g * 8 + j];
        }
    // C-layout biases + W4 column-vectors (k fixed, 4 rows per vector)
    f32x4 bb2v[2], bb3v[2], w4c[2][3];
    #pragma unroll
    for (int h = 0; h < 2; ++h)
        #pragma unroll
        for (int r = 0; r < 4; ++r) {
            const int row = 16 * h + 4 * g + r;
            bb2v[h][r] = b2[row];
            bb3v[h][r] = b3[row];
            #pragma unroll
            for (int k = 0; k < 3; ++k) w4c[h][k][r] = W4[row * 3 + k];
        }

    const int ntiles = (N + 15) >> 4;
    const int nwaves = gridDim.x * WAVES_PER_BLOCK;
    const f32x4 vzero = {0.f, 0.f, 0.f, 0.f};

    for (int tile = blockIdx.x * WAVES_PER_BLOCK + wid; tile < ntiles; tile += nwaves) {
        int s = tile * 16 + n16;
        if (s >= N) s = N - 1;
        const f32x4 X0 = splat4(x[3 * s + 0]);
        const f32x4 X1 = splat4(x[3 * s + 1]);
        const f32x4 X2 = splat4(x[3 * s + 2]);

        // ---- layer 1 (exact fp32, packed), directly in B-layout ----
        f32x4 vFv[2], v0v[2], v1v[2], v2v[2];
        #pragma unroll
        for (int c = 0; c < 2; ++c) {
            f32x4 z = __builtin_elementwise_fma(X0, w1v[0][c], bb1v[c]);
            z = __builtin_elementwise_fma(X1, w1v[1][c], z);
            z = __builtin_elementwise_fma(X2, w1v[2][c], z);
            f32x4 hv, sv;
            act_hs4(z, hv, sv);
            vFv[c] = hv;
            v0v[c] = sv * w1v[0][c];
            v1v[c] = sv * w1v[1][c];
            v2v[c] = sv * w1v[2][c];
        }

        // ---- layer 2 ----
        f32x4 aF[2], a0[2], a1[2], a2[2];
        aF[0] = bb2v[0]; aF[1] = bb2v[1];
        a0[0] = a0[1] = a1[0] = a1[1] = a2[0] = a2[1] = vzero;

        f16x8 bh, bl;
        fsplit8v(vFv[0], vFv[1], bh, bl);     // forward B: full split
        aF[0] = mfma2f(w2[0], bh, bl, aF[0]);
        aF[1] = mfma2f(w2[1], bh, bl, aF[1]);
        f16x8 tb = pack8v(v0v[0], v0v[1]);    // tangents: single f16
        a0[0] = mfma1t(w2[0], tb, a0[0]);
        a0[1] = mfma1t(w2[1], tb, a0[1]);
        tb = pack8v(v1v[0], v1v[1]);
        a1[0] = mfma1t(w2[0], tb, a1[0]);
        a1[1] = mfma1t(w2[1], tb, a1[1]);
        tb = pack8v(v2v[0], v2v[1]);
        a2[0] = mfma1t(w2[0], tb, a2[0]);
        a2[1] = mfma1t(w2[1], tb, a2[1]);

        // ---- boundary: act + diag-scale, packed, in C-layout ----
        #pragma unroll
        for (int h = 0; h < 2; ++h) {
            f32x4 hv, sv;
            act_hs4(aF[h], hv, sv);
            aF[h] = hv;                       // h2
            a0[h] *= sv;
            a1[h] *= sv;
            a2[h] *= sv;
        }

        // ---- layer 3: C-frags feed B directly (K-permuted weights) ----
        f32x4 zF[2], u0[2], u1[2], u2[2];
        zF[0] = bb3v[0]; zF[1] = bb3v[1];
        u0[0] = u0[1] = u1[0] = u1[1] = u2[0] = u2[1] = vzero;

        fsplit8v(aF[0], aF[1], bh, bl);
        zF[0] = mfma2f(w3[0], bh, bl, zF[0]);
        zF[1] = mfma2f(w3[1], bh, bl, zF[1]);
        tb = pack8v(a0[0], a0[1]);
        u0[0] = mfma1t(w3[0], tb, u0[0]);
        u0[1] = mfma1t(w3[1], tb, u0[1]);
        tb = pack8v(a1[0], a1[1]);
        u1[0] = mfma1t(w3[0], tb, u1[0]);
        u1[1] = mfma1t(w3[1], tb, u1[1]);
        tb = pack8v(a2[0], a2[1]);
        u2[0] = mfma1t(w3[0], tb, u2[0]);
        u2[1] = mfma1t(w3[1], tb, u2[1]);

        // ---- layer 4 + trace combine, packed across the 4 held rows ----
        // out0 = Σ t1*W4[:,0] + t2*W4[:,1]; out1 = Σ -t0*W4[:,0] + t2*W4[:,2];
        // out2 = Σ -t0*W4[:,1] - t1*W4[:,2]
        f32x4 O0 = vzero, O1 = vzero, O2 = vzero;
        #pragma unroll
        for (int h = 0; h < 2; ++h) {
            const f32x4 S  = sigmoid4(zF[h]);
            const f32x4 T0 = S * u0[h];
            const f32x4 T1 = S * u1[h];
            const f32x4 T2 = S * u2[h];
            O0 = __builtin_elementwise_fma(T1, w4c[h][0],
                 __builtin_elementwise_fma(T2, w4c[h][1], O0));
            O1 = __builtin_elementwise_fma(-T0, w4c[h][0],
                 __builtin_elementwise_fma(T2, w4c[h][2], O1));
            O2 = __builtin_elementwise_fma(-T0, w4c[h][1],
                 __builtin_elementwise_fma(-T1, w4c[h][2], O2));
        }
        float o0 = (O0[0] + O0[1]) + (O0[2] + O0[3]);
        float o1 = (O1[0] + O1[1]) + (O1[2] + O1[3]);
        float o2 = (O2[0] + O2[1]) + (O2[2] + O2[3]);

        o0 += __shfl_xor(o0, 16); o0 += __shfl_xor(o0, 32);
        o1 += __shfl_xor(o1, 16); o1 += __shfl_xor(o1, 32);
        o2 += __shfl_xor(o2, 16); o2 += __shfl_xor(o2, 32);

        if (g == 0) {
            out[3 * s + 0] = o0;
            out[3 * s + 1] = o1;
            out[3 * s + 2] = o2;
        }
    }
}

extern "C" void kernel_launch(void* const* d_in, const int* in_sizes, int n_in,
                              void* d_out, int out_size, void* d_ws, size_t ws_size,
                              hipStream_t stream)
{
    const float* x  = (const float*)d_in[0];
    const float* W1 = (const float*)d_in[1];
    const float* b1 = (const float*)d_in[2];
    const float* W2 = (const float*)d_in[3];
    const float* b2 = (const float*)d_in[4];
    const float* W3 = (const float*)d_in[5];
    const float* b3 = (const float*)d_in[6];
    const float* W4 = (const float*)d_in[7];
    // d_in[8] = b4 unused: constant offset cancels in the Jacobian.
    float* out = (float*)d_out;

    const int N = in_sizes[0] / 3;
    presdiv_kernel<<<NBLK, NTHR, 0, stream>>>(x, W1, b1, W2, b2, W3, b3, W4, out, N);
}

// Round 5
// 134.951 us; speedup vs baseline: 1.1129x; 1.0164x over previous
//
#include <hip/hip_runtime.h>
#include <math.h>

#define NTHR 256
#define WAVES_PER_BLOCK 4
#define NBLK 4096

typedef __attribute__((ext_vector_type(8))) _Float16 f16x8;   // MFMA A/B frag (4 VGPRs)
typedef __attribute__((ext_vector_type(2))) _Float16 half2v;
typedef __attribute__((ext_vector_type(4))) float f32x4;      // MFMA C/D frag + packed math
typedef __attribute__((ext_vector_type(4))) unsigned uint4v;

#define CEXP 28.85390082f     // 20 * log2(e)
#define KLOG 0.03465735903f   // ln(2) / 20

// raw gfx950 transcendentals: v_exp_f32 is 2^x, v_log_f32 is log2(x)
#define EXP2F(v) __builtin_amdgcn_exp2f(v)
#define LOG2F(v) __builtin_amdgcn_logf(v)

static __device__ __forceinline__ f32x4 splat4(float v) { return (f32x4){v, v, v, v}; }

// Vectorized softplus(beta=20) + derivative (proven fastest variant, R0).
// h = max(z,0) + KLOG*l, l = log2(1+2^(-|CEXP z|)); s = 1 - 2^(-CEXP*max(z,0) - l)
static __device__ __forceinline__ void act_hs4(f32x4 z, f32x4& h, f32x4& s) {
    f32x4 az = __builtin_elementwise_abs(splat4(CEXP) * z);
    f32x4 e;
    #pragma unroll
    for (int i = 0; i < 4; ++i) e[i] = EXP2F(-az[i]);
    f32x4 p = splat4(1.0f) + e;
    f32x4 l;
    #pragma unroll
    for (int i = 0; i < 4; ++i) l[i] = LOG2F(p[i]);
    f32x4 zp = __builtin_elementwise_max(z, splat4(0.0f));
    f32x4 q  = __builtin_elementwise_fma(splat4(-CEXP), zp, -l);
    f32x4 t;
    #pragma unroll
    for (int i = 0; i < 4; ++i) t[i] = EXP2F(q[i]);
    s = splat4(1.0f) - t;
    h = __builtin_elementwise_fma(splat4(KLOG), l, zp);
}

// sigmoid(20z) vectorized; select-free (exp2 overflow->inf, rcp(inf)->0)
static __device__ __forceinline__ f32x4 sigmoid4(f32x4 z) {
    f32x4 cz = splat4(-CEXP) * z;
    f32x4 e;
    #pragma unroll
    for (int i = 0; i < 4; ++i) e[i] = EXP2F(cz[i]);
    f32x4 p = splat4(1.0f) + e;
    f32x4 r;
    #pragma unroll
    for (int i = 0; i < 4; ++i) r[i] = __builtin_amdgcn_rcpf(p[i]);
    return r;
}

// pack 2 floats -> 2 f16 in one v_cvt_pkrtz_f16_f32
static __device__ __forceinline__ unsigned pk(float a, float b) {
    return __builtin_bit_cast(unsigned, __builtin_amdgcn_cvt_pkrtz(a, b));
}

// two f32x4 chunks -> single-f16 B operand (tangent streams)
static __device__ __forceinline__ f16x8 pack8v(const f32x4& a, const f32x4& b) {
    uint4v u = {pk(a[0], a[1]), pk(a[2], a[3]), pk(b[0], b[1]), pk(b[2], b[3])};
    return __builtin_bit_cast(f16x8, u);
}
// two f32x4 chunks -> f16 hi/lo split B operand (forward stream, residual ~2^-22)
static __device__ __forceinline__ void fsplit8v(const f32x4& a, const f32x4& b,
                                                f16x8& hi, f16x8& lo) {
    unsigned h[4], l[4];
    #pragma unroll
    for (int p2 = 0; p2 < 2; ++p2) {
        float u0 = a[2 * p2], u1 = a[2 * p2 + 1];
        unsigned hp = pk(u0, u1);
        half2v hh = __builtin_bit_cast(half2v, hp);
        h[p2] = hp;
        l[p2] = pk(u0 - (float)hh[0], u1 - (float)hh[1]);
        float w0 = b[2 * p2], w1 = b[2 * p2 + 1];
        unsigned hq = pk(w0, w1);
        half2v hh2 = __builtin_bit_cast(half2v, hq);
        h[2 + p2] = hq;
        l[2 + p2] = pk(w0 - (float)hh2[0], w1 - (float)hh2[1]);
    }
    hi = __builtin_bit_cast(f16x8, (uint4v){h[0], h[1], h[2], h[3]});
    lo = __builtin_bit_cast(f16x8, (uint4v){l[0], l[1], l[2], l[3]});
}

// forward, single-f16 weight: D += W*Bh + W*Bl
static __device__ __forceinline__ f32x4 mfma2f(f16x8 w, f16x8 bh, f16x8 bl, f32x4 c) {
    c = __builtin_amdgcn_mfma_f32_16x16x32_f16(w, bh, c, 0, 0, 0);
    c = __builtin_amdgcn_mfma_f32_16x16x32_f16(w, bl, c, 0, 0, 0);
    return c;
}
// tangent, single-f16 both sides: one MFMA
static __device__ __forceinline__ f32x4 mfma1t(f16x8 w, f16x8 b, f32x4 c) {
    return __builtin_amdgcn_mfma_f32_16x16x32_f16(w, b, c, 0, 0, 0);
}

// __launch_bounds__(256, 4): force allocator to fit VGPR+AGPR <= 128/wave so
// >=4 waves/SIMD are resident (R0-R4 evidence: unified-file pressure ~225 regs
// capped residency at ~2.25 waves/SIMD; the stream-serial body below shrinks
// peak live state to make 128 feasible without spills).
__global__ void __launch_bounds__(NTHR, 4)
presdiv_kernel(const float* __restrict__ x,
               const float* __restrict__ W1, const float* __restrict__ b1,
               const float* __restrict__ W2, const float* __restrict__ b2,
               const float* __restrict__ W3, const float* __restrict__ b3,
               const float* __restrict__ W4,
               float* __restrict__ out, int N)
{
    const int lane = threadIdx.x & 63;
    const int wid  = threadIdx.x >> 6;
    const int n16  = lane & 15;        // sample-within-tile / MFMA col
    const int g    = lane >> 4;        // quad

    // ---- persistent weights (per lane), single f16 (RTN) ----
    f16x8 w2[2], w3[2];
    #pragma unroll
    for (int h = 0; h < 2; ++h) {
        #pragma unroll
        for (int j = 0; j < 8; ++j) {
            const int k2 = g * 8 + j;
            w2[h][j] = (_Float16)W2[k2 * 32 + 16 * h + n16];
            const int k3 = (j < 4) ? (4 * g + j) : (16 + 4 * g + (j - 4));
            w3[h][j] = (_Float16)W3[k3 * 32 + 16 * h + n16];
        }
    }
    // layer-1 rows + bias, vectorized in 2 chunks of 4 features
    f32x4 w1v[3][2], bb1v[2];
    #pragma unroll
    for (int c = 0; c < 2; ++c)
        #pragma unroll
        for (int i = 0; i < 4; ++i) {
            const int j = 4 * c + i;
            bb1v[c][i] = b1[g * 8 + j];
            #pragma unroll
            for (int d = 0; d < 3; ++d) w1v[d][c][i] = W1[d * 32 + g * 8 + j];
        }
    // C-layout biases + W4 column-vectors (k fixed, 4 rows per vector)
    f32x4 bb2v[2], bb3v[2], w4c[2][3];
    #pragma unroll
    for (int h = 0; h < 2; ++h)
        #pragma unroll
        for (int r = 0; r < 4; ++r) {
            const int row = 16 * h + 4 * g + r;
            bb2v[h][r] = b2[row];
            bb3v[h][r] = b3[row];
            #pragma unroll
            for (int k = 0; k < 3; ++k) w4c[h][k][r] = W4[row * 3 + k];
        }

    const int ntiles = (N + 15) >> 4;
    const int nwaves = gridDim.x * WAVES_PER_BLOCK;
    const f32x4 vzero = {0.f, 0.f, 0.f, 0.f};

    for (int tile = blockIdx.x * WAVES_PER_BLOCK + wid; tile < ntiles; tile += nwaves) {
        int s = tile * 16 + n16;
        if (s >= N) s = N - 1;
        const f32x4 X0 = splat4(x[3 * s + 0]);
        const f32x4 X1 = splat4(x[3 * s + 1]);
        const f32x4 X2 = splat4(x[3 * s + 2]);

        // ---- layer 1 (exact fp32, packed), directly in B-layout ----
        f32x4 vFv[2], t0v[2], t1v[2], t2v[2];
        #pragma unroll
        for (int c = 0; c < 2; ++c) {
            f32x4 z = __builtin_elementwise_fma(X0, w1v[0][c], bb1v[c]);
            z = __builtin_elementwise_fma(X1, w1v[1][c], z);
            z = __builtin_elementwise_fma(X2, w1v[2][c], z);
            f32x4 hv, sv;
            act_hs4(z, hv, sv);
            vFv[c] = hv;
            t0v[c] = sv * w1v[0][c];
            t1v[c] = sv * w1v[1][c];
            t2v[c] = sv * w1v[2][c];
        }
        // pack tangent B-operands immediately: 3 x f16x8 (12 regs) replaces
        // 6 x f32x4 (24 regs) of live state for the rest of the tile.
        const f16x8 tb0 = pack8v(t0v[0], t0v[1]);
        const f16x8 tb1 = pack8v(t1v[0], t1v[1]);
        const f16x8 tb2 = pack8v(t2v[0], t2v[1]);

        // ---- forward path to completion: aF -> act -> zF -> S ----
        f16x8 bh, bl;
        fsplit8v(vFv[0], vFv[1], bh, bl);
        f32x4 aF0 = mfma2f(w2[0], bh, bl, bb2v[0]);
        f32x4 aF1 = mfma2f(w2[1], bh, bl, bb2v[1]);

        f32x4 hF0, hF1, sv0, sv1;
        act_hs4(aF0, hF0, sv0);
        act_hs4(aF1, hF1, sv1);

        fsplit8v(hF0, hF1, bh, bl);
        const f32x4 zF0 = mfma2f(w3[0], bh, bl, bb3v[0]);
        const f32x4 zF1 = mfma2f(w3[1], bh, bl, bb3v[1]);
        const f32x4 S0 = sigmoid4(zF0);
        const f32x4 S1 = sigmoid4(zF1);

        // ---- tangent streams, one at a time (minimal live state) ----
        // combine: O0 =  T1*W4[:,0] + T2*W4[:,1]
        //          O1 = -T0*W4[:,0] + T2*W4[:,2]
        //          O2 = -T0*W4[:,1] - T1*W4[:,2]
        f32x4 O0 = vzero, O1 = vzero, O2 = vzero;

        {   // d = 0 -> T0
            f32x4 a0 = mfma1t(w2[0], tb0, vzero) * sv0;
            f32x4 a1 = mfma1t(w2[1], tb0, vzero) * sv1;
            const f16x8 tp = pack8v(a0, a1);
            const f32x4 Ta = S0 * mfma1t(w3[0], tp, vzero);
            const f32x4 Tb = S1 * mfma1t(w3[1], tp, vzero);
            O1 = __builtin_elementwise_fma(-Ta, w4c[0][0],
                 __builtin_elementwise_fma(-Tb, w4c[1][0], O1));
            O2 = __builtin_elementwise_fma(-Ta, w4c[0][1],
                 __builtin_elementwise_fma(-Tb, w4c[1][1], O2));
        }
        {   // d = 1 -> T1
            f32x4 a0 = mfma1t(w2[0], tb1, vzero) * sv0;
            f32x4 a1 = mfma1t(w2[1], tb1, vzero) * sv1;
            const f16x8 tp = pack8v(a0, a1);
            const f32x4 Ta = S0 * mfma1t(w3[0], tp, vzero);
            const f32x4 Tb = S1 * mfma1t(w3[1], tp, vzero);
            O0 = __builtin_elementwise_fma(Ta, w4c[0][0],
                 __builtin_elementwise_fma(Tb, w4c[1][0], O0));
            O2 = __builtin_elementwise_fma(-Ta, w4c[0][2],
                 __builtin_elementwise_fma(-Tb, w4c[1][2], O2));
        }
        {   // d = 2 -> T2
            f32x4 a0 = mfma1t(w2[0], tb2, vzero) * sv0;
            f32x4 a1 = mfma1t(w2[1], tb2, vzero) * sv1;
            const f16x8 tp = pack8v(a0, a1);
            const f32x4 Ta = S0 * mfma1t(w3[0], tp, vzero);
            const f32x4 Tb = S1 * mfma1t(w3[1], tp, vzero);
            O0 = __builtin_elementwise_fma(Ta, w4c[0][1],
                 __builtin_elementwise_fma(Tb, w4c[1][1], O0));
            O1 = __builtin_elementwise_fma(Ta, w4c[0][2],
                 __builtin_elementwise_fma(Tb, w4c[1][2], O1));
        }

        float o0 = (O0[0] + O0[1]) + (O0[2] + O0[3]);
        float o1 = (O1[0] + O1[1]) + (O1[2] + O1[3]);
        float o2 = (O2[0] + O2[1]) + (O2[2] + O2[3]);

        o0 += __shfl_xor(o0, 16); o0 += __shfl_xor(o0, 32);
        o1 += __shfl_xor(o1, 16); o1 += __shfl_xor(o1, 32);
        o2 += __shfl_xor(o2, 16); o2 += __shfl_xor(o2, 32);

        if (g == 0) {
            out[3 * s + 0] = o0;
            out[3 * s + 1] = o1;
            out[3 * s + 2] = o2;
        }
    }
}

extern "C" void kernel_launch(void* const* d_in, const int* in_sizes, int n_in,
                              void* d_out, int out_size, void* d_ws, size_t ws_size,
                              hipStream_t stream)
{
    const float* x  = (const float*)d_in[0];
    const float* W1 = (const float*)d_in[1];
    const float* b1 = (const float*)d_in[2];
    const float* W2 = (const float*)d_in[3];
    const float* b2 = (const float*)d_in[4];
    const float* W3 = (const float*)d_in[5];
    const float* b3 = (const float*)d_in[6];
    const float* W4 = (const float*)d_in[7];
    // d_in[8] = b4 unused: constant offset cancels in the Jacobian.
    float* out = (float*)d_out;

    const int N = in_sizes[0] / 3;
    presdiv_kernel<<<NBLK, NTHR, 0, stream>>>(x, W1, b1, W2, b2, W3, b3, W4, out, N);
}